// Round 11
// baseline (339.307 us; speedup 1.0000x reference)
//
#include <hip/hip_runtime.h>
#include <hip/hip_bf16.h>

#define BB 4
#define SS 2048
#define DD 1024
#define HH 16
#define DHH 64
#define MM (BB*SS)   // 8192
#define KK 1024
#define NT 32        // K-tiles of 32 (gemm256_k)

typedef __bf16 bf16;
typedef __attribute__((ext_vector_type(4))) __bf16 bf16x4;
typedef __attribute__((ext_vector_type(8))) __bf16 bf16x8;
typedef __attribute__((ext_vector_type(4))) float floatx4;

#define C_SCALE 0.1803368801111164f   // 0.125 * log2(e), folded into Wq/bq

// async global->LDS DMA, 16 B per lane, lands at wave-uniform base + lane*16
#define GLD16(g, l) __builtin_amdgcn_global_load_lds( \
    (__attribute__((address_space(1))) void*)(g), \
    (__attribute__((address_space(3))) void*)(l), 16, 0, 0)

// ------------------------------------------------------------ fused prep:
// blocks [0,4096):       x f32 -> bf16 (2048 elems/block)
// blocks [4096,5120):    W transpose+cast (64x64 tile each, z = idx>>8)
// blocks [5120,5132):    bias concat (bq scaled)
__global__ __launch_bounds__(256) void prep_k(const float* __restrict__ x, bf16* __restrict__ xc,
                                              const float* __restrict__ W0, const float* __restrict__ W1,
                                              const float* __restrict__ W2, const float* __restrict__ W3,
                                              bf16* __restrict__ Wt,
                                              const float* __restrict__ bq, const float* __restrict__ bk,
                                              const float* __restrict__ bv, float* __restrict__ bcat) {
    __shared__ bf16 tile[64][65];
    const int bxg = blockIdx.x;
    if (bxg < 4096) {
        size_t o = ((size_t)bxg * 256 + threadIdx.x) * 8;
        float4 f0 = *(const float4*)(x + o);
        float4 f1 = *(const float4*)(x + o + 4);
        bf16x8 v;
        v[0] = (bf16)f0.x; v[1] = (bf16)f0.y; v[2] = (bf16)f0.z; v[3] = (bf16)f0.w;
        v[4] = (bf16)f1.x; v[5] = (bf16)f1.y; v[6] = (bf16)f1.z; v[7] = (bf16)f1.w;
        *(bf16x8*)(xc + o) = v;
    } else if (bxg < 5120) {
        int idx = bxg - 4096;
        int z = idx >> 8, rem = idx & 255;
        int by = (rem >> 4) * 64, bx = (rem & 15) * 64;
        const float* W = (z == 0) ? W0 : (z == 1) ? W1 : (z == 2) ? W2 : W3;
        float sc = (z == 0) ? C_SCALE : 1.0f;
        bf16* Wo = Wt + (size_t)z * DD * DD;
        int tx = threadIdx.x & 63, ty = threadIdx.x >> 6;
        for (int i = ty; i < 64; i += 4)
            tile[i][tx] = (bf16)(W[(size_t)(by + i) * DD + bx + tx] * sc);
        __syncthreads();
        for (int i = ty; i < 64; i += 4)
            Wo[(size_t)(bx + i) * DD + by + tx] = tile[tx][i];
    } else {
        int i = (bxg - 5120) * 256 + threadIdx.x;
        float v;
        if (i < 1024)      v = bq[i] * C_SCALE;
        else if (i < 2048) v = bk[i - 1024];
        else               v = bv[i - 2048];
        bcat[i] = v;
    }
}

// ------------------------------------------------------------ 256x128 GEMM, BK=32
// (r2/r6/r8 proven best: 8 waves 2Mx4N, 4-deep LDS ring 96 KB, counted vmcnt,
// T2 swizzle (conflicts=0 measured), T5 setprio). Both projections. FROZEN.
// out = A[m][k] * Bt[n][k] + bias[n]
// MODE 0: float out[m*DD+n]
// MODE 1: fused QKV routing; out base of contiguous Qb|Kb|Vb; which=n0>>10
//   Q,K: bf16 [((b*H+h)*S+s)*DH+dh]
//   V:   bf16 [((b*H+h)*DH+dh)*S + sigma(s)]  sigma = 4*(s&15)+((s>>4)&3) within 64-tile
#define BUFEL 12288   // elements per ring buffer (24 KB)
template<int MODE>
__global__ __launch_bounds__(512) void gemm256_k(const bf16* __restrict__ A,
                                                 const bf16* __restrict__ Bt,
                                                 const float* __restrict__ bias,
                                                 void* __restrict__ outv) {
    __shared__ __align__(16) bf16 ldsb[4 * BUFEL];

    const int tid = threadIdx.x;
    const int l = tid & 63, w = tid >> 6;
    const int quad = l >> 4, lane16 = l & 15;
    const int wm = w >> 2, wn = w & 3;

    // bijective XCD swizzle (nwg % 8 == 0 for both launches)
    const int nwg = gridDim.x * gridDim.y;
    int bid = blockIdx.y * gridDim.x + blockIdx.x;
    int chunk = nwg >> 3;
    int swz = (bid & 7) * chunk + (bid >> 3);
    const int m0 = (swz / gridDim.x) * 256;
    const int n0 = (swz % gridDim.x) * 128;

    // staging: 24 slices of 1 KB; wave w owns slices 3w..3w+2
    const bf16* srcp[3];
    int dstoff[3];
#pragma unroll
    for (int j = 0; j < 3; j++) {
        int s = w * 3 + j;
        int a = l >> 2, bq4 = l & 3;
        int rl = (s & 15) * 16 + a;                 // row within A (s<16) or B (s>=16)
        int colel = ((bq4 * 16) ^ (((rl >> 1) & 3) << 4)) >> 1;  // pre-swizzled source col
        srcp[j] = (s < 16 ? A + (size_t)(m0 + rl) * KK
                          : Bt + (size_t)(n0 + rl) * KK) + colel;
        dstoff[j] = s * 512 + l * 8;                // linear LDS dest (elems)
    }

#define STAGE(tt) { bf16* db_ = ldsb + ((tt) & 3) * BUFEL; \
    _Pragma("unroll") \
    for (int j = 0; j < 3; j++) GLD16(srcp[j] + (tt) * 32, db_ + dstoff[j]); }

    STAGE(0);
    STAGE(1);
    asm volatile("s_waitcnt vmcnt(3)" ::: "memory");
    __builtin_amdgcn_sched_barrier(0);
    __builtin_amdgcn_s_barrier();

    const int gsw = (quad ^ ((lane16 >> 1) & 3)) * 8;   // read-side swizzled granule
    floatx4 acc[8][2] = {};

#pragma unroll 1
    for (int t = 0; t < NT; t++) {
        const bf16* Ab = ldsb + (t & 3) * BUFEL;
        const bf16* Bb = Ab + 8192;
        bf16x8 af[8], bv2[2];
#pragma unroll
        for (int mf = 0; mf < 8; mf++)
            af[mf] = *(const bf16x8*)(Ab + (wm * 128 + mf * 16 + lane16) * 32 + gsw);
#pragma unroll
        for (int nf = 0; nf < 2; nf++)
            bv2[nf] = *(const bf16x8*)(Bb + (wn * 32 + nf * 16 + lane16) * 32 + gsw);

        if (t + 2 < NT) STAGE(t + 2);               // ring: never the buffer being read

        __builtin_amdgcn_s_barrier();
        asm volatile("s_waitcnt lgkmcnt(0)" ::: "memory");
        __builtin_amdgcn_sched_barrier(0);

        __builtin_amdgcn_s_setprio(1);
#pragma unroll
        for (int mf = 0; mf < 8; mf++)
#pragma unroll
            for (int nf = 0; nf < 2; nf++)
                acc[mf][nf] = __builtin_amdgcn_mfma_f32_16x16x32_bf16(af[mf], bv2[nf], acc[mf][nf], 0, 0, 0);
        __builtin_amdgcn_s_setprio(0);

        if (t < NT - 1) {
            if (t + 2 < NT) { asm volatile("s_waitcnt vmcnt(3)" ::: "memory"); }
            else            { asm volatile("s_waitcnt vmcnt(0)" ::: "memory"); }
            __builtin_amdgcn_sched_barrier(0);
            __builtin_amdgcn_s_barrier();
        }
    }
#undef STAGE

    if (MODE == 0) {
        float* out = (float*)outv;
#pragma unroll
        for (int mf = 0; mf < 8; mf++)
#pragma unroll
            for (int nf = 0; nf < 2; nf++)
#pragma unroll
                for (int r = 0; r < 4; r++) {
                    int m = m0 + wm * 128 + mf * 16 + quad * 4 + r;
                    int n = n0 + wn * 32 + nf * 16 + lane16;
                    out[(size_t)m * DD + n] = acc[mf][nf][r] + bias[n];
                }
    } else {
        int which = n0 >> 10;
        bf16* dst = (bf16*)outv + (size_t)which * MM * DD;
#pragma unroll
        for (int mf = 0; mf < 8; mf++)
#pragma unroll
            for (int nf = 0; nf < 2; nf++)
#pragma unroll
                for (int r = 0; r < 4; r++) {
                    int m = m0 + wm * 128 + mf * 16 + quad * 4 + r;
                    int n = n0 + wn * 32 + nf * 16 + lane16;
                    float v = acc[mf][nf][r] + bias[n];
                    int n1 = n & 1023;
                    int b = m >> 11, s = m & (SS - 1);
                    int h = n1 >> 6, dh = n1 & 63;
                    if (which < 2) {
                        dst[((size_t)(b * HH + h) * SS + s) * DHH + dh] = (bf16)v;
                    } else {
                        int st = s & 63;
                        int sp = (s & ~63) | ((st & 15) * 4 + (st >> 4));   // sigma for packed P-store
                        dst[((size_t)(b * HH + h) * DHH + dh) * SS + sp] = (bf16)v;
                    }
                }
    }
}

// ------------------------------------------------------------ attention
// NO K/V LDS staging, NO barriers (m169 pattern): K/V are L2-resident per XCD
// (grid (64,8), bh = blockIdx.x -> all 8 q-blocks of a bh on one XCD; K+V per
// bh = 512 KB, 8 bh/XCD = 4 MB = L2). Each wave loads its MFMA fragments
// directly from global; waves fully independent -> compiler/TLP hide latency.
// r4 shape: 4 waves x 32 queries (2 subtiles), kf/vf amortized over 2 subtiles.
// Work-balanced pairing: y processes q-tile y (small) then 15-y (big) = 34 iters.
// Q: [bh][s][dh] pre-scaled; K: [bh][s][dh]; Vt: [bh][dh][sigma(s)]
__global__ __launch_bounds__(256, 2) void attn_k(const bf16* __restrict__ Q,
                                                 const bf16* __restrict__ K,
                                                 const bf16* __restrict__ Vt,
                                                 bf16* __restrict__ ctx) {
    __shared__ __align__(16) bf16 ps[4][16 * 72];   // per-wave P scratch only

    const int tid = threadIdx.x;
    const int l = tid & 63, w = tid >> 6;           // 4 waves
    const int quad = l >> 4, lane16 = l & 15;
    const int bh = blockIdx.x;                      // XCD affinity
    const bf16* Qp = Q  + (size_t)bh * SS * DHH;
    const bf16* Kp = K  + (size_t)bh * SS * DHH;
    const bf16* Vp = Vt + (size_t)bh * DHH * SS;
    const int b = bh >> 4, h = bh & 15;

#pragma unroll 1
    for (int pp = 0; pp < 2; pp++) {
        const int qt = pp ? (SS / 128 - 1) - blockIdx.y : blockIdx.y;
        const int q0 = qt * 128;

        bf16x8 qf[2][2];
#pragma unroll
        for (int sub = 0; sub < 2; sub++)
#pragma unroll
            for (int kk = 0; kk < 2; kk++)
                qf[sub][kk] = *(const bf16x8*)(
                    Qp + (size_t)(q0 + w * 32 + sub * 16 + lane16) * DHH + kk * 32 + quad * 8);

        floatx4 o_acc[2][4] = {};
        float l_part[2][4] = {};

        const int nkt = 2 * qt + 2;
#pragma unroll 1
        for (int kt = 0; kt < nkt; kt++) {
            const int kb0 = kt * 64;

            // direct global fragment loads (L2-hit via bh->XCD affinity)
            bf16x8 kf[2][4], vf[2][4];
#pragma unroll
            for (int kk = 0; kk < 2; kk++)
#pragma unroll
                for (int nb = 0; nb < 4; nb++) {
                    kf[kk][nb] = *(const bf16x8*)(
                        Kp + (size_t)(kb0 + nb * 16 + lane16) * DHH + kk * 32 + quad * 8);
                    vf[kk][nb] = *(const bf16x8*)(
                        Vp + (size_t)(nb * 16 + lane16) * SS + kb0 + kk * 32 + quad * 8);
                }

#pragma unroll
            for (int sub = 0; sub < 2; sub++) {
                const int qsb = q0 + w * 32 + sub * 16;
                if (kb0 > qsb + 15) continue;               // fully masked (wave-uniform)

                floatx4 sc[4] = {};
                __builtin_amdgcn_s_setprio(1);
#pragma unroll
                for (int nb = 0; nb < 4; nb++) {
                    sc[nb] = __builtin_amdgcn_mfma_f32_16x16x32_bf16(qf[sub][0], kf[0][nb], sc[nb], 0, 0, 0);
                    sc[nb] = __builtin_amdgcn_mfma_f32_16x16x32_bf16(qf[sub][1], kf[1][nb], sc[nb], 0, 0, 0);
                }
                __builtin_amdgcn_s_setprio(0);

                float p[4][4];
                if (kb0 + 63 > qsb) {                       // diagonal: per-element mask
#pragma unroll
                    for (int nb = 0; nb < 4; nb++) {
                        int key = kb0 + nb * 16 + lane16;
#pragma unroll
                        for (int r = 0; r < 4; r++) {
                            int qg = qsb + quad * 4 + r;
                            float e = exp2f(sc[nb][r]);
                            e = (key <= qg) ? e : 0.f;
                            p[nb][r] = e;
                            l_part[sub][r] += e;
                        }
                    }
                } else {
#pragma unroll
                    for (int nb = 0; nb < 4; nb++)
#pragma unroll
                        for (int r = 0; r < 4; r++) {
                            float e = exp2f(sc[nb][r]);
                            p[nb][r] = e;
                            l_part[sub][r] += e;
                        }
                }

                // packed P-store: column sigma(key)=4*lane16+nb -> one b64 per row
#pragma unroll
                for (int r = 0; r < 4; r++) {
                    bf16x4 pk;
                    pk[0] = (bf16)p[0][r]; pk[1] = (bf16)p[1][r];
                    pk[2] = (bf16)p[2][r]; pk[3] = (bf16)p[3][r];
                    *(bf16x4*)(&ps[w][(quad * 4 + r) * 72 + lane16 * 4]) = pk;
                }
                asm volatile("s_waitcnt lgkmcnt(0)" ::: "memory");

                __builtin_amdgcn_s_setprio(1);
#pragma unroll
                for (int kk = 0; kk < 2; kk++) {
                    bf16x8 af2 = *(const bf16x8*)(&ps[w][lane16 * 72 + kk * 32 + quad * 8]);
#pragma unroll
                    for (int nb = 0; nb < 4; nb++)
                        o_acc[sub][nb] = __builtin_amdgcn_mfma_f32_16x16x32_bf16(af2, vf[kk][nb], o_acc[sub][nb], 0, 0, 0);
                }
                __builtin_amdgcn_s_setprio(0);
            }
        }

#pragma unroll
        for (int off = 1; off < 16; off <<= 1)
#pragma unroll
            for (int sub = 0; sub < 2; sub++)
#pragma unroll
                for (int r = 0; r < 4; r++)
                    l_part[sub][r] += __shfl_xor(l_part[sub][r], off, 64);

#pragma unroll
        for (int sub = 0; sub < 2; sub++)
#pragma unroll
            for (int r = 0; r < 4; r++) {
                float inv = 1.0f / l_part[sub][r];
                int s = q0 + w * 32 + sub * 16 + quad * 4 + r;
#pragma unroll
                for (int nb = 0; nb < 4; nb++) {
                    int dh = nb * 16 + lane16;
                    ctx[((size_t)(b * SS + s)) * DD + h * DHH + dh] = (bf16)(o_acc[sub][nb][r] * inv);
                }
            }
    }
}

// ------------------------------------------------------------ launch
extern "C" void kernel_launch(void* const* d_in, const int* in_sizes, int n_in,
                              void* d_out, int out_size, void* d_ws, size_t ws_size,
                              hipStream_t stream) {
    const float* x  = (const float*)d_in[0];
    const float* Wq = (const float*)d_in[1];
    const float* bq = (const float*)d_in[2];
    const float* Wk = (const float*)d_in[3];
    const float* bk = (const float*)d_in[4];
    const float* Wv = (const float*)d_in[5];
    const float* bv = (const float*)d_in[6];
    const float* Wo = (const float*)d_in[7];
    const float* bo = (const float*)d_in[8];

    bf16* ws   = (bf16*)d_ws;
    bf16* xc   = ws;                               // 16 MB  x as bf16
    bf16* Wcat = xc + (size_t)MM * DD;             //  8 MB  [Wq^T*c | Wk^T | Wv^T | Wo^T]
    bf16* Qb   = Wcat + (size_t)4 * DD * DD;       // 16 MB each, contiguous Q|K|V
    bf16* Kb   = Qb + (size_t)MM * DD;
    bf16* Vb   = Kb + (size_t)MM * DD;
    bf16* Cb   = Vb + (size_t)MM * DD;             // 16 MB  context
    float* bcat = (float*)(Cb + (size_t)MM * DD);  // 12 KB

    prep_k<<<dim3(5132), dim3(256), 0, stream>>>(x, xc, Wq, Wk, Wv, Wo, Wcat,
                                                 bq, bk, bv, bcat);

    gemm256_k<1><<<dim3(3 * DD / 128, MM / 256), dim3(512), 0, stream>>>(xc, Wcat, bcat, Qb);
    attn_k<<<dim3(BB * HH, SS / 256), dim3(256), 0, stream>>>(Qb, Kb, Vb, Cb);
    gemm256_k<0><<<dim3(DD / 128, MM / 256), dim3(512), 0, stream>>>(
        Cb, Wcat + (size_t)3 * DD * DD, bo, d_out);
}

// Round 12
// 278.409 us; speedup vs baseline: 1.2187x; 1.2187x over previous
//
#include <hip/hip_runtime.h>
#include <hip/hip_bf16.h>

#define BB 4
#define SS 2048
#define DD 1024
#define HH 16
#define DHH 64
#define MM (BB*SS)   // 8192
#define KK 1024
#define NT 32        // K-tiles of 32 (gemm256_k)

typedef __bf16 bf16;
typedef __attribute__((ext_vector_type(4))) __bf16 bf16x4;
typedef __attribute__((ext_vector_type(8))) __bf16 bf16x8;
typedef __attribute__((ext_vector_type(4))) float floatx4;

#define C_SCALE 0.1803368801111164f   // 0.125 * log2(e), folded into Wq/bq

// async global->LDS DMA, 16 B per lane, lands at wave-uniform base + lane*16
#define GLD16(g, l) __builtin_amdgcn_global_load_lds( \
    (__attribute__((address_space(1))) void*)(g), \
    (__attribute__((address_space(3))) void*)(l), 16, 0, 0)

// ------------------------------------------------------------ fused prep:
// blocks [0,4096):       x f32 -> bf16 (2048 elems/block)
// blocks [4096,5120):    W transpose+cast (64x64 tile each, z = idx>>8)
// blocks [5120,5132):    bias concat (bq scaled)
__global__ __launch_bounds__(256) void prep_k(const float* __restrict__ x, bf16* __restrict__ xc,
                                              const float* __restrict__ W0, const float* __restrict__ W1,
                                              const float* __restrict__ W2, const float* __restrict__ W3,
                                              bf16* __restrict__ Wt,
                                              const float* __restrict__ bq, const float* __restrict__ bk,
                                              const float* __restrict__ bv, float* __restrict__ bcat) {
    __shared__ bf16 tile[64][65];
    const int bxg = blockIdx.x;
    if (bxg < 4096) {
        size_t o = ((size_t)bxg * 256 + threadIdx.x) * 8;
        float4 f0 = *(const float4*)(x + o);
        float4 f1 = *(const float4*)(x + o + 4);
        bf16x8 v;
        v[0] = (bf16)f0.x; v[1] = (bf16)f0.y; v[2] = (bf16)f0.z; v[3] = (bf16)f0.w;
        v[4] = (bf16)f1.x; v[5] = (bf16)f1.y; v[6] = (bf16)f1.z; v[7] = (bf16)f1.w;
        *(bf16x8*)(xc + o) = v;
    } else if (bxg < 5120) {
        int idx = bxg - 4096;
        int z = idx >> 8, rem = idx & 255;
        int by = (rem >> 4) * 64, bx = (rem & 15) * 64;
        const float* W = (z == 0) ? W0 : (z == 1) ? W1 : (z == 2) ? W2 : W3;
        float sc = (z == 0) ? C_SCALE : 1.0f;
        bf16* Wo = Wt + (size_t)z * DD * DD;
        int tx = threadIdx.x & 63, ty = threadIdx.x >> 6;
        for (int i = ty; i < 64; i += 4)
            tile[i][tx] = (bf16)(W[(size_t)(by + i) * DD + bx + tx] * sc);
        __syncthreads();
        for (int i = ty; i < 64; i += 4)
            Wo[(size_t)(bx + i) * DD + by + tx] = tile[tx][i];
    } else {
        int i = (bxg - 5120) * 256 + threadIdx.x;
        float v;
        if (i < 1024)      v = bq[i] * C_SCALE;
        else if (i < 2048) v = bk[i - 1024];
        else               v = bv[i - 2048];
        bcat[i] = v;
    }
}

// ------------------------------------------------------------ 256x128 GEMM, BK=32
// (r2/r6/r8 proven best: 8 waves 2Mx4N, 4-deep LDS ring 96 KB, counted vmcnt,
// T2 swizzle (conflicts=0 measured), T5 setprio). QKV projection. FROZEN.
// out = A[m][k] * Bt[n][k] + bias[n]
// MODE 0: float out[m*DD+n]
// MODE 1: fused QKV routing; out base of contiguous Qb|Kb|Vb; which=n0>>10
//   Q,K: bf16 [((b*H+h)*S+s)*DH+dh]
//   V:   bf16 [((b*H+h)*DH+dh)*S + sigma(s)]  sigma = 4*(s&15)+((s>>4)&3) within 64-tile
#define BUFEL 12288   // elements per ring buffer (24 KB)
template<int MODE>
__global__ __launch_bounds__(512) void gemm256_k(const bf16* __restrict__ A,
                                                 const bf16* __restrict__ Bt,
                                                 const float* __restrict__ bias,
                                                 void* __restrict__ outv) {
    __shared__ __align__(16) bf16 ldsb[4 * BUFEL];

    const int tid = threadIdx.x;
    const int l = tid & 63, w = tid >> 6;
    const int quad = l >> 4, lane16 = l & 15;
    const int wm = w >> 2, wn = w & 3;

    // bijective XCD swizzle (nwg % 8 == 0)
    const int nwg = gridDim.x * gridDim.y;
    int bid = blockIdx.y * gridDim.x + blockIdx.x;
    int chunk = nwg >> 3;
    int swz = (bid & 7) * chunk + (bid >> 3);
    const int m0 = (swz / gridDim.x) * 256;
    const int n0 = (swz % gridDim.x) * 128;

    // staging: 24 slices of 1 KB; wave w owns slices 3w..3w+2
    const bf16* srcp[3];
    int dstoff[3];
#pragma unroll
    for (int j = 0; j < 3; j++) {
        int s = w * 3 + j;
        int a = l >> 2, bq4 = l & 3;
        int rl = (s & 15) * 16 + a;                 // row within A (s<16) or B (s>=16)
        int colel = ((bq4 * 16) ^ (((rl >> 1) & 3) << 4)) >> 1;  // pre-swizzled source col
        srcp[j] = (s < 16 ? A + (size_t)(m0 + rl) * KK
                          : Bt + (size_t)(n0 + rl) * KK) + colel;
        dstoff[j] = s * 512 + l * 8;                // linear LDS dest (elems)
    }

#define STAGE(tt) { bf16* db_ = ldsb + ((tt) & 3) * BUFEL; \
    _Pragma("unroll") \
    for (int j = 0; j < 3; j++) GLD16(srcp[j] + (tt) * 32, db_ + dstoff[j]); }

    STAGE(0);
    STAGE(1);
    asm volatile("s_waitcnt vmcnt(3)" ::: "memory");
    __builtin_amdgcn_sched_barrier(0);
    __builtin_amdgcn_s_barrier();

    const int gsw = (quad ^ ((lane16 >> 1) & 3)) * 8;   // read-side swizzled granule
    floatx4 acc[8][2] = {};

#pragma unroll 1
    for (int t = 0; t < NT; t++) {
        const bf16* Ab = ldsb + (t & 3) * BUFEL;
        const bf16* Bb = Ab + 8192;
        bf16x8 af[8], bv2[2];
#pragma unroll
        for (int mf = 0; mf < 8; mf++)
            af[mf] = *(const bf16x8*)(Ab + (wm * 128 + mf * 16 + lane16) * 32 + gsw);
#pragma unroll
        for (int nf = 0; nf < 2; nf++)
            bv2[nf] = *(const bf16x8*)(Bb + (wn * 32 + nf * 16 + lane16) * 32 + gsw);

        if (t + 2 < NT) STAGE(t + 2);               // ring: never the buffer being read

        __builtin_amdgcn_s_barrier();
        asm volatile("s_waitcnt lgkmcnt(0)" ::: "memory");
        __builtin_amdgcn_sched_barrier(0);

        __builtin_amdgcn_s_setprio(1);
#pragma unroll
        for (int mf = 0; mf < 8; mf++)
#pragma unroll
            for (int nf = 0; nf < 2; nf++)
                acc[mf][nf] = __builtin_amdgcn_mfma_f32_16x16x32_bf16(af[mf], bv2[nf], acc[mf][nf], 0, 0, 0);
        __builtin_amdgcn_s_setprio(0);

        if (t < NT - 1) {
            if (t + 2 < NT) { asm volatile("s_waitcnt vmcnt(3)" ::: "memory"); }
            else            { asm volatile("s_waitcnt vmcnt(0)" ::: "memory"); }
            __builtin_amdgcn_sched_barrier(0);
            __builtin_amdgcn_s_barrier();
        }
    }
#undef STAGE

    if (MODE == 0) {
        float* out = (float*)outv;
#pragma unroll
        for (int mf = 0; mf < 8; mf++)
#pragma unroll
            for (int nf = 0; nf < 2; nf++)
#pragma unroll
                for (int r = 0; r < 4; r++) {
                    int m = m0 + wm * 128 + mf * 16 + quad * 4 + r;
                    int n = n0 + wn * 32 + nf * 16 + lane16;
                    out[(size_t)m * DD + n] = acc[mf][nf][r] + bias[n];
                }
    } else {
        int which = n0 >> 10;
        bf16* dst = (bf16*)outv + (size_t)which * MM * DD;
#pragma unroll
        for (int mf = 0; mf < 8; mf++)
#pragma unroll
            for (int nf = 0; nf < 2; nf++)
#pragma unroll
                for (int r = 0; r < 4; r++) {
                    int m = m0 + wm * 128 + mf * 16 + quad * 4 + r;
                    int n = n0 + wn * 32 + nf * 16 + lane16;
                    float v = acc[mf][nf][r] + bias[n];
                    int n1 = n & 1023;
                    int b = m >> 11, s = m & (SS - 1);
                    int h = n1 >> 6, dh = n1 & 63;
                    if (which < 2) {
                        dst[((size_t)(b * HH + h) * SS + s) * DHH + dh] = (bf16)v;
                    } else {
                        int st = s & 63;
                        int sp = (s & ~63) | ((st & 15) * 4 + (st >> 4));   // sigma for packed P-store
                        dst[((size_t)(b * HH + h) * DHH + dh) * SS + sp] = (bf16)v;
                    }
                }
    }
}

// ------------------------------------------------------------ 128x256 GEMM, BK=64
// (R7-measured: 8-phase, no sched_barrier, 8 waves 2Mx4N wave tile 64x64,
// double-buffered 96 KB, counted vmcnt(4) at phases 4/8, T2 swizzle, setprio).
// Used for the OUT-PROJECTION only: grid (4,64) = 256 blocks = 1 exact CU round.
#define TBUF 24576    // elems per buffer (48 KB): A[128][64] @0, B[256][64] @8192
#define NT2 16        // K-tiles of 64
#define NI  8         // iters of 2 K-tiles
template<int MODE>
__global__ __launch_bounds__(512, 2) void gemm8p_k(const bf16* __restrict__ A,
                                                   const bf16* __restrict__ Bt,
                                                   const float* __restrict__ bias,
                                                   void* __restrict__ outv) {
    __shared__ __align__(16) bf16 ldsb[2 * TBUF];   // 96 KB

    const int tid = threadIdx.x;
    const int l = tid & 63, w = tid >> 6;
    const int quad = l >> 4, lane16 = l & 15;
    const int wm = w >> 2, wn = w & 3;            // 2M x 4N waves, wave tile 64x64

    const int nwg = gridDim.x * gridDim.y;
    int bid = blockIdx.y * gridDim.x + blockIdx.x;
    int chunk = nwg >> 3;
    int swz = (bid & 7) * chunk + (bid >> 3);
    const int m0 = (swz / gridDim.x) * 128;
    const int n0 = (swz % gridDim.x) * 256;

    const int rr = tid >> 3;                       // row within 64-row slab
    const int swc = ((tid & 7) ^ (rr & 7)) << 3;   // pre-swizzled source col (elems)
    const bf16* pA = A  + (size_t)(m0 + rr) * KK + swc;
    const bf16* pB = Bt + (size_t)(n0 + rr) * KK + swc;

#define STG_A(tk, be) { _Pragma("unroll") for (int j = 0; j < 2; j++) \
    GLD16(pA + (size_t)(j*64) * KK + (tk)*64, ldsb + (be) + (j*512 + tid)*8); }
#define STG_B(h, tk, be) { _Pragma("unroll") for (int j = 0; j < 2; j++) \
    GLD16(pB + (size_t)((h)*128 + j*64) * KK + (tk)*64, \
          ldsb + (be) + 8192 + (h)*8192 + (j*512 + tid)*8); }

    const int swk0 = (quad ^ (lane16 & 7)) << 3;
    const int swk1 = ((4 | quad) ^ (lane16 & 7)) << 3;

    bf16x8 af[4][2];
    bf16x8 bfr[4][2];
    floatx4 acc[4][4] = {};
    int bb = 0;

#define LDA2(qm) { _Pragma("unroll") for (int mi = 0; mi < 2; mi++) { \
    int mfl = (qm)*2 + mi; \
    af[mfl][0] = *(const bf16x8*)(ldsb + bb + (wm*64 + mfl*16 + lane16)*64 + swk0); \
    af[mfl][1] = *(const bf16x8*)(ldsb + bb + (wm*64 + mfl*16 + lane16)*64 + swk1); } }
#define LDB2(qn) { _Pragma("unroll") for (int ni = 0; ni < 2; ni++) { \
    int nfl = (qn)*2 + ni; \
    bfr[nfl][0] = *(const bf16x8*)(ldsb + bb + 8192 + (wn*64 + nfl*16 + lane16)*64 + swk0); \
    bfr[nfl][1] = *(const bf16x8*)(ldsb + bb + 8192 + (wn*64 + nfl*16 + lane16)*64 + swk1); } }
#define MM8(qm, qn) { _Pragma("unroll") for (int mi = 0; mi < 2; mi++) \
    _Pragma("unroll") for (int ni = 0; ni < 2; ni++) \
    _Pragma("unroll") for (int kk = 0; kk < 2; kk++) \
    acc[(qm)*2+mi][(qn)*2+ni] = __builtin_amdgcn_mfma_f32_16x16x32_bf16( \
        af[(qm)*2+mi][kk], bfr[(qn)*2+ni][kk], acc[(qm)*2+mi][(qn)*2+ni], 0, 0, 0); }

#define PH_MID  __builtin_amdgcn_s_barrier(); \
    asm volatile("s_waitcnt lgkmcnt(0)" ::: "memory"); \
    __builtin_amdgcn_s_setprio(1);
#define PH_END  __builtin_amdgcn_s_setprio(0); __builtin_amdgcn_s_barrier();
#define PH_END_V4 __builtin_amdgcn_s_setprio(0); \
    asm volatile("s_waitcnt vmcnt(4)" ::: "memory"); \
    __builtin_amdgcn_s_barrier();
#define PH_END_V0 __builtin_amdgcn_s_setprio(0); \
    asm volatile("s_waitcnt vmcnt(0)" ::: "memory"); \
    __builtin_amdgcn_s_barrier();

    STG_A(0, 0); STG_B(0, 0, 0); STG_B(1, 0, 0);
    STG_B(0, 1, TBUF); STG_B(1, 1, TBUF);
    asm volatile("s_waitcnt vmcnt(4)" ::: "memory");
    __builtin_amdgcn_s_barrier();

#pragma unroll 1
    for (int i = 0; i < NI; i++) {
        const int t1 = 2*i + 1, t2 = 2*i + 2, t3 = 2*i + 3;
        bb = 0;
        LDA2(0); LDB2(0); STG_A(t1, TBUF);              PH_MID; MM8(0,0); PH_END;
        LDB2(1);                                        PH_MID; MM8(0,1); PH_END;
        LDA2(1); if (t2 < NT2) STG_B(0, t2, 0);         PH_MID; MM8(1,1); PH_END;
                 if (t2 < NT2) STG_B(1, t2, 0);         PH_MID; MM8(1,0);
        if (i < NI-1) { PH_END_V4 } else { PH_END_V0 }
        bb = TBUF;
        LDA2(0); LDB2(0); if (t2 < NT2) STG_A(t2, 0);   PH_MID; MM8(0,0); PH_END;
        LDB2(1);                                        PH_MID; MM8(0,1); PH_END;
        LDA2(1); if (t3 < NT2) STG_B(0, t3, TBUF);      PH_MID; MM8(1,1); PH_END;
                 if (t3 < NT2) STG_B(1, t3, TBUF);      PH_MID; MM8(1,0);
        if (i < NI-1) { PH_END_V4 } else { PH_END }
    }
#undef STG_A
#undef STG_B
#undef LDA2
#undef LDB2
#undef MM8
#undef PH_MID
#undef PH_END
#undef PH_END_V4
#undef PH_END_V0

    if (MODE == 0) {
        float* out = (float*)outv;
#pragma unroll
        for (int mf = 0; mf < 4; mf++)
#pragma unroll
            for (int nf = 0; nf < 4; nf++)
#pragma unroll
                for (int r = 0; r < 4; r++) {
                    int m = m0 + wm * 64 + mf * 16 + quad * 4 + r;
                    int n = n0 + wn * 64 + nf * 16 + lane16;
                    out[(size_t)m * DD + n] = acc[mf][nf][r] + bias[n];
                }
    } else {
        int which = n0 >> 10;
        bf16* dst = (bf16*)outv + (size_t)which * MM * DD;
#pragma unroll
        for (int mf = 0; mf < 4; mf++)
#pragma unroll
            for (int nf = 0; nf < 4; nf++)
#pragma unroll
                for (int r = 0; r < 4; r++) {
                    int m = m0 + wm * 64 + mf * 16 + quad * 4 + r;
                    int n = n0 + wn * 64 + nf * 16 + lane16;
                    float v = acc[mf][nf][r] + bias[n];
                    int n1 = n & 1023;
                    int b = m >> 11, s = m & (SS - 1);
                    int h = n1 >> 6, dh = n1 & 63;
                    if (which < 2) {
                        dst[((size_t)(b * HH + h) * SS + s) * DHH + dh] = (bf16)v;
                    } else {
                        int st = s & 63;
                        int sp = (s & ~63) | ((st & 15) * 4 + (st >> 4));
                        dst[((size_t)(b * HH + h) * DHH + dh) * SS + sp] = (bf16)v;
                    }
                }
    }
}

// ------------------------------------------------------------ attention
// (R7-measured form: 2 barriers/iter, reg prefetch, setprio, ps[4].)
// Work-balanced pairing: block x processes q-tile x (small) then 15-x (big);
// every block does exactly 34 K-tile iterations. Grid (8, 64), bh = blockIdx.y.
__global__ __launch_bounds__(256, 2) void attn_k(const bf16* __restrict__ Q,
                                                 const bf16* __restrict__ K,
                                                 const bf16* __restrict__ Vt,
                                                 bf16* __restrict__ ctx) {
    __shared__ __align__(16) bf16 ks[64 * 72];
    __shared__ __align__(16) bf16 vs[64 * 72];
    __shared__ __align__(16) bf16 ps[4][16 * 72];

    const int tid = threadIdx.x;
    const int l = tid & 63, w = tid >> 6;
    const int quad = l >> 4, lane16 = l & 15;
    const int bh = blockIdx.y;
    const bf16* Qp = Q  + (size_t)bh * SS * DHH;
    const bf16* Kp = K  + (size_t)bh * SS * DHH;
    const bf16* Vp = Vt + (size_t)bh * DHH * SS;
    const int row = tid >> 2, colc = (tid & 3) * 16;
    const int b = bh >> 4, h = bh & 15;

#pragma unroll 1
    for (int pp = 0; pp < 2; pp++) {
        const int qt = pp ? (SS / 128 - 1) - blockIdx.x : blockIdx.x;
        const int q0 = qt * 128;

        bf16x8 qf[2][2];
#pragma unroll
        for (int sub = 0; sub < 2; sub++)
#pragma unroll
            for (int kk = 0; kk < 2; kk++)
                qf[sub][kk] = *(const bf16x8*)(
                    Qp + (size_t)(q0 + w * 32 + sub * 16 + lane16) * DHH + kk * 32 + quad * 8);

        uint4 ka = *(const uint4*)(Kp + (size_t)row * DHH + colc);
        uint4 kb = *(const uint4*)(Kp + (size_t)row * DHH + colc + 8);
        uint4 va = *(const uint4*)(Vp + (size_t)row * SS + colc);
        uint4 vb = *(const uint4*)(Vp + (size_t)row * SS + colc + 8);

        floatx4 o_acc[2][4] = {};
        float l_part[2][4] = {};

        const int nkt = 2 * qt + 2;
        for (int kt = 0; kt < nkt; kt++) {
            __syncthreads();
            *(uint4*)(ks + row * 72 + colc)     = ka;
            *(uint4*)(ks + row * 72 + colc + 8) = kb;
            *(uint4*)(vs + row * 72 + colc)     = va;
            *(uint4*)(vs + row * 72 + colc + 8) = vb;
            if (kt + 1 < nkt) {
                const bf16* Kn = Kp + (size_t)(kt + 1) * 64 * DHH;
                const bf16* Vn = Vp + (kt + 1) * 64;
                ka = *(const uint4*)(Kn + (size_t)row * DHH + colc);
                kb = *(const uint4*)(Kn + (size_t)row * DHH + colc + 8);
                va = *(const uint4*)(Vn + (size_t)row * SS + colc);
                vb = *(const uint4*)(Vn + (size_t)row * SS + colc + 8);
            }
            __syncthreads();

            bf16x8 kf[2][4], vf[2][4];
#pragma unroll
            for (int kk = 0; kk < 2; kk++)
#pragma unroll
                for (int nb = 0; nb < 4; nb++) {
                    kf[kk][nb] = *(const bf16x8*)(ks + (nb * 16 + lane16) * 72 + kk * 32 + quad * 8);
                    vf[kk][nb] = *(const bf16x8*)(vs + (nb * 16 + lane16) * 72 + kk * 32 + quad * 8);
                }

            const int kb0 = kt * 64;
#pragma unroll
            for (int sub = 0; sub < 2; sub++) {
                const int qsb = q0 + w * 32 + sub * 16;
                if (kb0 > qsb + 15) continue;

                floatx4 sc[4] = {};
                __builtin_amdgcn_s_setprio(1);
#pragma unroll
                for (int nb = 0; nb < 4; nb++) {
                    sc[nb] = __builtin_amdgcn_mfma_f32_16x16x32_bf16(qf[sub][0], kf[0][nb], sc[nb], 0, 0, 0);
                    sc[nb] = __builtin_amdgcn_mfma_f32_16x16x32_bf16(qf[sub][1], kf[1][nb], sc[nb], 0, 0, 0);
                }
                __builtin_amdgcn_s_setprio(0);

                float p[4][4];
                if (kb0 + 63 > qsb) {
#pragma unroll
                    for (int nb = 0; nb < 4; nb++) {
                        int key = kb0 + nb * 16 + lane16;
#pragma unroll
                        for (int r = 0; r < 4; r++) {
                            int qg = qsb + quad * 4 + r;
                            float e = exp2f(sc[nb][r]);
                            e = (key <= qg) ? e : 0.f;
                            p[nb][r] = e;
                            l_part[sub][r] += e;
                        }
                    }
                } else {
#pragma unroll
                    for (int nb = 0; nb < 4; nb++)
#pragma unroll
                        for (int r = 0; r < 4; r++) {
                            float e = exp2f(sc[nb][r]);
                            p[nb][r] = e;
                            l_part[sub][r] += e;
                        }
                }

#pragma unroll
                for (int r = 0; r < 4; r++) {
                    bf16x4 pk;
                    pk[0] = (bf16)p[0][r]; pk[1] = (bf16)p[1][r];
                    pk[2] = (bf16)p[2][r]; pk[3] = (bf16)p[3][r];
                    *(bf16x4*)(&ps[w][(quad * 4 + r) * 72 + lane16 * 4]) = pk;
                }
                asm volatile("s_waitcnt lgkmcnt(0)" ::: "memory");

                __builtin_amdgcn_s_setprio(1);
#pragma unroll
                for (int kk = 0; kk < 2; kk++) {
                    bf16x8 af2 = *(const bf16x8*)(&ps[w][lane16 * 72 + kk * 32 + quad * 8]);
#pragma unroll
                    for (int nb = 0; nb < 4; nb++)
                        o_acc[sub][nb] = __builtin_amdgcn_mfma_f32_16x16x32_bf16(af2, vf[kk][nb], o_acc[sub][nb], 0, 0, 0);
                }
                __builtin_amdgcn_s_setprio(0);
            }
        }

#pragma unroll
        for (int off = 1; off < 16; off <<= 1)
#pragma unroll
            for (int sub = 0; sub < 2; sub++)
#pragma unroll
                for (int r = 0; r < 4; r++)
                    l_part[sub][r] += __shfl_xor(l_part[sub][r], off, 64);

#pragma unroll
        for (int sub = 0; sub < 2; sub++)
#pragma unroll
            for (int r = 0; r < 4; r++) {
                float inv = 1.0f / l_part[sub][r];
                int s = q0 + w * 32 + sub * 16 + quad * 4 + r;
#pragma unroll
                for (int nb = 0; nb < 4; nb++) {
                    int dh = nb * 16 + lane16;
                    ctx[((size_t)(b * SS + s)) * DD + h * DHH + dh] = (bf16)(o_acc[sub][nb][r] * inv);
                }
            }
    }
}

// ------------------------------------------------------------ launch
extern "C" void kernel_launch(void* const* d_in, const int* in_sizes, int n_in,
                              void* d_out, int out_size, void* d_ws, size_t ws_size,
                              hipStream_t stream) {
    const float* x  = (const float*)d_in[0];
    const float* Wq = (const float*)d_in[1];
    const float* bq = (const float*)d_in[2];
    const float* Wk = (const float*)d_in[3];
    const float* bk = (const float*)d_in[4];
    const float* Wv = (const float*)d_in[5];
    const float* bv = (const float*)d_in[6];
    const float* Wo = (const float*)d_in[7];
    const float* bo = (const float*)d_in[8];

    bf16* ws   = (bf16*)d_ws;
    bf16* xc   = ws;                               // 16 MB  x as bf16
    bf16* Wcat = xc + (size_t)MM * DD;             //  8 MB  [Wq^T*c | Wk^T | Wv^T | Wo^T]
    bf16* Qb   = Wcat + (size_t)4 * DD * DD;       // 16 MB each, contiguous Q|K|V
    bf16* Kb   = Qb + (size_t)MM * DD;
    bf16* Vb   = Kb + (size_t)MM * DD;
    bf16* Cb   = Vb + (size_t)MM * DD;             // 16 MB  context
    float* bcat = (float*)(Cb + (size_t)MM * DD);  // 12 KB

    prep_k<<<dim3(5132), dim3(256), 0, stream>>>(x, xc, Wq, Wk, Wv, Wo, Wcat,
                                                 bq, bk, bv, bcat);

    gemm256_k<1><<<dim3(3 * DD / 128, MM / 256), dim3(512), 0, stream>>>(xc, Wcat, bcat, Qb);
    attn_k<<<dim3(SS / 256, BB * HH), dim3(256), 0, stream>>>(Qb, Kb, Vb, Cb);
    gemm8p_k<0><<<dim3(DD / 256, MM / 128), dim3(512), 0, stream>>>(
        Cb, Wcat + (size_t)3 * DD * DD, bo, d_out);
}